// Round 2
// baseline (447.900 us; speedup 1.0000x reference)
//
#include <hip/hip_runtime.h>
#include <hip/hip_bf16.h>
#include <math.h>

// ---------------------------------------------------------------------------
// GATv2 x2 layers, N=50000, d=128, E=800000 (+N self loops).
// edge_index arrives as int32 (harness converts integer inputs to int).
// Pipeline per call:
//   CSR build (zero -> hist -> scan x3 -> fill)   [shared by both layers]
//   gemm: xl = X@Wl+bl, xr = X@Wr+br              [one launch, blockIdx.y]
//   agg : per-dst wave, softmax without max-shift (logits are O(10), fp32-safe)
//         out[dst] = sum(exp(e)*xl[src]) / sum(exp(e)) + bo  [+leaky 0.01 L0]
// Workspace (~55 MB): xl, xr, offs, deg/cursor, bsum, boff, colsrc.
// Inter-layer activation h lives in d_out (dead before final agg overwrite).
// ---------------------------------------------------------------------------

#define LRELU_ATT 0.2f
#define LRELU_ACT 0.01f

// ---------------- CSR build ----------------

__global__ void zero_kernel(int* __restrict__ p, int n) {
    int i = blockIdx.x * blockDim.x + threadIdx.x;
    if (i < n) p[i] = 0;
}

__global__ void hist_kernel(const int* __restrict__ ei, int E, int Etot,
                            int* __restrict__ deg) {
    int e = blockIdx.x * blockDim.x + threadIdx.x;
    if (e >= Etot) return;
    int d = (e < E) ? ei[E + e] : (e - E);
    atomicAdd(&deg[d], 1);
}

__global__ void scan1_kernel(const int* __restrict__ deg, int n,
                             int* __restrict__ offs, int* __restrict__ bsum) {
    __shared__ int s[256];
    int tid = threadIdx.x;
    int i = blockIdx.x * 256 + tid;
    int v = (i < n) ? deg[i] : 0;
    s[tid] = v;
    __syncthreads();
    int sum = v;
    #pragma unroll
    for (int d = 1; d < 256; d <<= 1) {
        int t = (tid >= d) ? s[tid - d] : 0;
        __syncthreads();
        sum += t;
        s[tid] = sum;
        __syncthreads();
    }
    if (i < n) offs[i] = sum - v;              // exclusive within block
    if (tid == 255) bsum[blockIdx.x] = sum;    // block total
}

__global__ void scan2_kernel(int* __restrict__ bsum, int nb,
                             int* __restrict__ boff) {
    __shared__ int s[256];
    int tid = threadIdx.x;
    int v = (tid < nb) ? bsum[tid] : 0;
    s[tid] = v;
    __syncthreads();
    int sum = v;
    #pragma unroll
    for (int d = 1; d < 256; d <<= 1) {
        int t = (tid >= d) ? s[tid - d] : 0;
        __syncthreads();
        sum += t;
        s[tid] = sum;
        __syncthreads();
    }
    if (tid < nb) boff[tid] = sum - v;         // exclusive block offsets
}

__global__ void scan3_kernel(int* __restrict__ offs, const int* __restrict__ boff,
                             int n, int Etot, int* __restrict__ cursor) {
    int i = blockIdx.x * 256 + threadIdx.x;
    if (i < n) {
        int o = offs[i] + boff[blockIdx.x];
        offs[i] = o;
        cursor[i] = o;
    }
    if (i == 0) offs[n] = Etot;
}

__global__ void fill_kernel(const int* __restrict__ ei, int E, int Etot,
                            int* __restrict__ cursor, int* __restrict__ col_src) {
    int e = blockIdx.x * blockDim.x + threadIdx.x;
    if (e >= Etot) return;
    int s, d;
    if (e < E) { s = ei[e]; d = ei[E + e]; }
    else       { s = d = e - E; }
    int pos = atomicAdd(&cursor[d], 1);
    col_src[pos] = s;
}

// ---------------- dual GEMM: xl = X@Wl+bl ; xr = X@Wr+br ----------------
// block: 256 thr; tile 64 rows x 128 cols; thread = 8 rows x 4 cols.
// blockIdx.y in {0,1} selects (Wl,bl,xl) / (Wr,br,xr).

__global__ __launch_bounds__(256) void gemm_dual_kernel(
    const float* __restrict__ X,
    const float* __restrict__ Wl, const float* __restrict__ bl,
    const float* __restrict__ Wr, const float* __restrict__ br,
    float* __restrict__ xl, float* __restrict__ xr, int n) {
    __shared__ float xs[64 * 128];
    const int tid = threadIdx.x;
    const int base = blockIdx.x * 64;

    // stage x tile (64 rows x 128 k) into LDS, float4-coalesced
    const float4* X4 = (const float4*)X;
    float4* xs4 = (float4*)xs;
    #pragma unroll
    for (int i = 0; i < 8; ++i) {
        int f = tid + i * 256;              // float4 index in tile (0..2047)
        int row = base + (f >> 5);          // 32 float4 per row
        float4 v = make_float4(0.f, 0.f, 0.f, 0.f);
        if (row < n) v = X4[(size_t)base * 32 + f];
        xs4[f] = v;
    }
    __syncthreads();

    const float* W  = blockIdx.y ? Wr : Wl;
    const float* bb = blockIdx.y ? br : bl;
    float* out      = blockIdx.y ? xr : xl;

    const int tc = tid & 31;                 // col group (4 cols each)
    const int tr = tid >> 5;                 // row group (8 rows each)
    const int col0 = tc * 4;
    const int r0 = tr * 8;

    float4 acc[8];
    #pragma unroll
    for (int r = 0; r < 8; ++r) acc[r] = make_float4(0.f, 0.f, 0.f, 0.f);

    for (int k = 0; k < 128; ++k) {
        float4 wv = *(const float4*)(W + (size_t)k * 128 + col0);
        #pragma unroll
        for (int r = 0; r < 8; ++r) {
            float xv = xs[(r0 + r) * 128 + k];
            acc[r].x += xv * wv.x;
            acc[r].y += xv * wv.y;
            acc[r].z += xv * wv.z;
            acc[r].w += xv * wv.w;
        }
    }

    float4 bv = *(const float4*)(bb + col0);
    #pragma unroll
    for (int r = 0; r < 8; ++r) {
        int row = base + r0 + r;
        if (row < n) {
            float4 o = make_float4(acc[r].x + bv.x, acc[r].y + bv.y,
                                   acc[r].z + bv.z, acc[r].w + bv.w);
            *(float4*)(out + (size_t)row * 128 + col0) = o;
        }
    }
}

// ---------------- fused attention + aggregation ----------------
// one 64-lane wave per dst node; lane owns channels (2l, 2l+1).
// softmax WITHOUT max-shift: logits ~N(0,1.3^2), exp safe in fp32.

__global__ __launch_bounds__(256) void gat_agg_kernel(
    const float* __restrict__ xl, const float* __restrict__ xr,
    const float* __restrict__ att, const float* __restrict__ bo,
    const int* __restrict__ offs, const int* __restrict__ col,
    float* __restrict__ out, int n, int apply_act) {
    const int wid  = (blockIdx.x * blockDim.x + threadIdx.x) >> 6;
    const int lane = threadIdx.x & 63;
    if (wid >= n) return;

    const float2 xr2  = ((const float2*)(xr + (size_t)wid * 128))[lane];
    const float2 att2 = ((const float2*)att)[lane];

    float accx = 0.f, accy = 0.f, denom = 0.f;
    const int b = offs[wid], e = offs[wid + 1];
    for (int i = b; i < e; ++i) {
        const int s = col[i];
        const float2 v = ((const float2*)(xl + (size_t)s * 128))[lane];
        float mx = v.x + xr2.x;
        float my = v.y + xr2.y;
        mx = mx > 0.f ? mx : LRELU_ATT * mx;
        my = my > 0.f ? my : LRELU_ATT * my;
        float p = mx * att2.x + my * att2.y;
        #pragma unroll
        for (int m = 1; m < 64; m <<= 1) p += __shfl_xor(p, m, 64);
        const float ex = __expf(p);
        accx += ex * v.x;
        accy += ex * v.y;
        denom += ex;
    }
    const float inv = 1.f / (denom + 1e-16f);
    const float2 bo2 = ((const float2*)bo)[lane];
    float ox = accx * inv + bo2.x;
    float oy = accy * inv + bo2.y;
    if (apply_act) {
        ox = ox > 0.f ? ox : LRELU_ACT * ox;
        oy = oy > 0.f ? oy : LRELU_ACT * oy;
    }
    ((float2*)(out + (size_t)wid * 128))[lane] = make_float2(ox, oy);
}

// ---------------- host launch ----------------

static inline size_t align_up(size_t x, size_t a) { return (x + a - 1) & ~(a - 1); }

extern "C" void kernel_launch(void* const* d_in, const int* in_sizes, int n_in,
                              void* d_out, int out_size, void* d_ws, size_t ws_size,
                              hipStream_t stream) {
    const float* x   = (const float*)d_in[0];
    const int*   ei  = (const int*)d_in[1];     // int32 per harness contract
    const float* Wl0 = (const float*)d_in[2];
    const float* bl0 = (const float*)d_in[3];
    const float* Wr0 = (const float*)d_in[4];
    const float* br0 = (const float*)d_in[5];
    const float* att0= (const float*)d_in[6];
    const float* bo0 = (const float*)d_in[7];
    const float* Wl1 = (const float*)d_in[8];
    const float* bl1 = (const float*)d_in[9];
    const float* Wr1 = (const float*)d_in[10];
    const float* br1 = (const float*)d_in[11];
    const float* att1= (const float*)d_in[12];
    const float* bo1 = (const float*)d_in[13];
    float* outp = (float*)d_out;

    const int N    = in_sizes[0] / 128;
    const int E    = in_sizes[1] / 2;
    const int Etot = E + N;

    // workspace layout (~55 MB)
    char* p = (char*)d_ws;
    size_t off = 0;
    const size_t feat_bytes = (size_t)N * 128 * sizeof(float);
    float* xl = (float*)(p + off); off = align_up(off + feat_bytes, 256);
    float* xr = (float*)(p + off); off = align_up(off + feat_bytes, 256);
    int* degcur = (int*)(p + off); off = align_up(off + (size_t)N * 4, 256);       // deg, then cursor
    int* offs   = (int*)(p + off); off = align_up(off + (size_t)(N + 1) * 4, 256);
    int* bsum   = (int*)(p + off); off = align_up(off + 256 * 4, 256);
    int* boff   = (int*)(p + off); off = align_up(off + 256 * 4, 256);
    int* colsrc = (int*)(p + off); off = align_up(off + (size_t)Etot * 4, 256);
    float* h = outp;                         // inter-layer activation in d_out
    (void)ws_size;

    const int nbScan = (N + 255) / 256;      // 196 for N=50000 (<=256 required)
    const int nbEdge = (Etot + 255) / 256;

    // ---- CSR build ----
    zero_kernel<<<nbScan, 256, 0, stream>>>(degcur, N);
    hist_kernel<<<nbEdge, 256, 0, stream>>>(ei, E, Etot, degcur);
    scan1_kernel<<<nbScan, 256, 0, stream>>>(degcur, N, offs, bsum);
    scan2_kernel<<<1, 256, 0, stream>>>(bsum, nbScan, boff);
    scan3_kernel<<<nbScan, 256, 0, stream>>>(offs, boff, N, Etot, degcur);
    fill_kernel<<<nbEdge, 256, 0, stream>>>(ei, E, Etot, degcur, colsrc);

    const int nbGemm = (N + 63) / 64;
    const int nbAgg  = (N + 3) / 4;          // 4 waves (dst nodes) per block

    // ---- layer 0 ----
    gemm_dual_kernel<<<dim3(nbGemm, 2), 256, 0, stream>>>(x, Wl0, bl0, Wr0, br0, xl, xr, N);
    gat_agg_kernel<<<nbAgg, 256, 0, stream>>>(xl, xr, att0, bo0, offs, colsrc, h, N, 1);

    // ---- layer 1 ----
    gemm_dual_kernel<<<dim3(nbGemm, 2), 256, 0, stream>>>(h, Wl1, bl1, Wr1, br1, xl, xr, N);
    gat_agg_kernel<<<nbAgg, 256, 0, stream>>>(xl, xr, att1, bo1, offs, colsrc, outp, N, 0);
}

// Round 3
// 347.058 us; speedup vs baseline: 1.2906x; 1.2906x over previous
//
#include <hip/hip_runtime.h>
#include <hip/hip_bf16.h>
#include <math.h>

// ---------------------------------------------------------------------------
// GATv2 x2 layers, N=50000, d=128, E=800000 (+N self loops).
// Round 3: (a) agg kernel 4x edge-unroll -> 4 independent shfl-butterflies
// in flight (was 1; latency-bound at VALUBusy=32%); (b) GEMM k-unroll x4 with
// ds_read_b128 LDS reads (was scalar ds_read_b32, 1024/lane).
// ---------------------------------------------------------------------------

#define LRELU_ATT 0.2f
#define LRELU_ACT 0.01f

// ---------------- CSR build ----------------

__global__ void zero_kernel(int* __restrict__ p, int n) {
    int i = blockIdx.x * blockDim.x + threadIdx.x;
    if (i < n) p[i] = 0;
}

__global__ void hist_kernel(const int* __restrict__ ei, int E, int Etot,
                            int* __restrict__ deg) {
    int e = blockIdx.x * blockDim.x + threadIdx.x;
    if (e >= Etot) return;
    int d = (e < E) ? ei[E + e] : (e - E);
    atomicAdd(&deg[d], 1);
}

__global__ void scan1_kernel(const int* __restrict__ deg, int n,
                             int* __restrict__ offs, int* __restrict__ bsum) {
    __shared__ int s[256];
    int tid = threadIdx.x;
    int i = blockIdx.x * 256 + tid;
    int v = (i < n) ? deg[i] : 0;
    s[tid] = v;
    __syncthreads();
    int sum = v;
    #pragma unroll
    for (int d = 1; d < 256; d <<= 1) {
        int t = (tid >= d) ? s[tid - d] : 0;
        __syncthreads();
        sum += t;
        s[tid] = sum;
        __syncthreads();
    }
    if (i < n) offs[i] = sum - v;
    if (tid == 255) bsum[blockIdx.x] = sum;
}

__global__ void scan2_kernel(int* __restrict__ bsum, int nb,
                             int* __restrict__ boff) {
    __shared__ int s[256];
    int tid = threadIdx.x;
    int v = (tid < nb) ? bsum[tid] : 0;
    s[tid] = v;
    __syncthreads();
    int sum = v;
    #pragma unroll
    for (int d = 1; d < 256; d <<= 1) {
        int t = (tid >= d) ? s[tid - d] : 0;
        __syncthreads();
        sum += t;
        s[tid] = sum;
        __syncthreads();
    }
    if (tid < nb) boff[tid] = sum - v;
}

__global__ void scan3_kernel(int* __restrict__ offs, const int* __restrict__ boff,
                             int n, int Etot, int* __restrict__ cursor) {
    int i = blockIdx.x * 256 + threadIdx.x;
    if (i < n) {
        int o = offs[i] + boff[blockIdx.x];
        offs[i] = o;
        cursor[i] = o;
    }
    if (i == 0) offs[n] = Etot;
}

__global__ void fill_kernel(const int* __restrict__ ei, int E, int Etot,
                            int* __restrict__ cursor, int* __restrict__ col_src) {
    int e = blockIdx.x * blockDim.x + threadIdx.x;
    if (e >= Etot) return;
    int s, d;
    if (e < E) { s = ei[e]; d = ei[E + e]; }
    else       { s = d = e - E; }
    int pos = atomicAdd(&cursor[d], 1);
    col_src[pos] = s;
}

// ---------------- dual GEMM: xl = X@Wl+bl ; xr = X@Wr+br ----------------
// block: 256 thr; tile 64 rows x 128 cols; thread = 8 rows x 4 cols.
// k unrolled x4, LDS reads are float4 (ds_read_b128).

__global__ __launch_bounds__(256) void gemm_dual_kernel(
    const float* __restrict__ X,
    const float* __restrict__ Wl, const float* __restrict__ bl,
    const float* __restrict__ Wr, const float* __restrict__ br,
    float* __restrict__ xl, float* __restrict__ xr, int n) {
    __shared__ float xs[64 * 128];
    const int tid = threadIdx.x;
    const int base = blockIdx.x * 64;

    const float4* X4 = (const float4*)X;
    float4* xs4 = (float4*)xs;
    #pragma unroll
    for (int i = 0; i < 8; ++i) {
        int f = tid + i * 256;
        int row = base + (f >> 5);
        float4 v = make_float4(0.f, 0.f, 0.f, 0.f);
        if (row < n) v = X4[(size_t)base * 32 + f];
        xs4[f] = v;
    }
    __syncthreads();

    const float* W  = blockIdx.y ? Wr : Wl;
    const float* bb = blockIdx.y ? br : bl;
    float* out      = blockIdx.y ? xr : xl;

    const int tc = tid & 31;
    const int tr = tid >> 5;
    const int col0 = tc * 4;
    const int r0 = tr * 8;

    float4 acc[8];
    #pragma unroll
    for (int r = 0; r < 8; ++r) acc[r] = make_float4(0.f, 0.f, 0.f, 0.f);

    for (int k = 0; k < 128; k += 4) {
        float4 wv0 = *(const float4*)(W + (size_t)(k + 0) * 128 + col0);
        float4 wv1 = *(const float4*)(W + (size_t)(k + 1) * 128 + col0);
        float4 wv2 = *(const float4*)(W + (size_t)(k + 2) * 128 + col0);
        float4 wv3 = *(const float4*)(W + (size_t)(k + 3) * 128 + col0);
        #pragma unroll
        for (int r = 0; r < 8; ++r) {
            float4 xv = *(const float4*)(xs + (r0 + r) * 128 + k);  // ds_read_b128
            acc[r].x += xv.x * wv0.x + xv.y * wv1.x + xv.z * wv2.x + xv.w * wv3.x;
            acc[r].y += xv.x * wv0.y + xv.y * wv1.y + xv.z * wv2.y + xv.w * wv3.y;
            acc[r].z += xv.x * wv0.z + xv.y * wv1.z + xv.z * wv2.z + xv.w * wv3.z;
            acc[r].w += xv.x * wv0.w + xv.y * wv1.w + xv.z * wv2.w + xv.w * wv3.w;
        }
    }

    float4 bv = *(const float4*)(bb + col0);
    #pragma unroll
    for (int r = 0; r < 8; ++r) {
        int row = base + r0 + r;
        if (row < n) {
            float4 o = make_float4(acc[r].x + bv.x, acc[r].y + bv.y,
                                   acc[r].z + bv.z, acc[r].w + bv.w);
            *(float4*)(out + (size_t)row * 128 + col0) = o;
        }
    }
}

// ---------------- fused attention + aggregation ----------------
// one 64-lane wave per dst node; lane owns channels (2l, 2l+1).
// 4x edge unroll: 4 independent shfl butterflies + gathers in flight.

__device__ __forceinline__ float edge_logit(float2 v, float2 xr2, float2 att2) {
    float mx = v.x + xr2.x;
    float my = v.y + xr2.y;
    mx = mx > 0.f ? mx : LRELU_ATT * mx;
    my = my > 0.f ? my : LRELU_ATT * my;
    return mx * att2.x + my * att2.y;
}

__global__ __launch_bounds__(256) void gat_agg_kernel(
    const float* __restrict__ xl, const float* __restrict__ xr,
    const float* __restrict__ att, const float* __restrict__ bo,
    const int* __restrict__ offs, const int* __restrict__ col,
    float* __restrict__ out, int n, int apply_act) {
    const int wid  = (blockIdx.x * blockDim.x + threadIdx.x) >> 6;
    const int lane = threadIdx.x & 63;
    if (wid >= n) return;

    const float2 xr2  = ((const float2*)(xr + (size_t)wid * 128))[lane];
    const float2 att2 = ((const float2*)att)[lane];
    const float2* xl2 = (const float2*)xl;

    float accx = 0.f, accy = 0.f, denom = 0.f;
    const int b = offs[wid], e = offs[wid + 1];

    int i = b;
    for (; i + 4 <= e; i += 4) {
        const int s0 = col[i + 0], s1 = col[i + 1], s2 = col[i + 2], s3 = col[i + 3];
        const float2 v0 = xl2[(size_t)s0 * 64 + lane];
        const float2 v1 = xl2[(size_t)s1 * 64 + lane];
        const float2 v2 = xl2[(size_t)s2 * 64 + lane];
        const float2 v3 = xl2[(size_t)s3 * 64 + lane];
        float p0 = edge_logit(v0, xr2, att2);
        float p1 = edge_logit(v1, xr2, att2);
        float p2 = edge_logit(v2, xr2, att2);
        float p3 = edge_logit(v3, xr2, att2);
        #pragma unroll
        for (int m = 1; m < 64; m <<= 1) {
            p0 += __shfl_xor(p0, m, 64);
            p1 += __shfl_xor(p1, m, 64);
            p2 += __shfl_xor(p2, m, 64);
            p3 += __shfl_xor(p3, m, 64);
        }
        const float e0 = __expf(p0), e1 = __expf(p1), e2 = __expf(p2), e3 = __expf(p3);
        accx += e0 * v0.x + e1 * v1.x + e2 * v2.x + e3 * v3.x;
        accy += e0 * v0.y + e1 * v1.y + e2 * v2.y + e3 * v3.y;
        denom += (e0 + e1) + (e2 + e3);
    }
    for (; i < e; ++i) {
        const int s = col[i];
        const float2 v = xl2[(size_t)s * 64 + lane];
        float p = edge_logit(v, xr2, att2);
        #pragma unroll
        for (int m = 1; m < 64; m <<= 1) p += __shfl_xor(p, m, 64);
        const float ex = __expf(p);
        accx += ex * v.x;
        accy += ex * v.y;
        denom += ex;
    }

    const float inv = 1.f / (denom + 1e-16f);
    const float2 bo2 = ((const float2*)bo)[lane];
    float ox = accx * inv + bo2.x;
    float oy = accy * inv + bo2.y;
    if (apply_act) {
        ox = ox > 0.f ? ox : LRELU_ACT * ox;
        oy = oy > 0.f ? oy : LRELU_ACT * oy;
    }
    ((float2*)(out + (size_t)wid * 128))[lane] = make_float2(ox, oy);
}

// ---------------- host launch ----------------

static inline size_t align_up(size_t x, size_t a) { return (x + a - 1) & ~(a - 1); }

extern "C" void kernel_launch(void* const* d_in, const int* in_sizes, int n_in,
                              void* d_out, int out_size, void* d_ws, size_t ws_size,
                              hipStream_t stream) {
    const float* x   = (const float*)d_in[0];
    const int*   ei  = (const int*)d_in[1];     // int32 per harness contract
    const float* Wl0 = (const float*)d_in[2];
    const float* bl0 = (const float*)d_in[3];
    const float* Wr0 = (const float*)d_in[4];
    const float* br0 = (const float*)d_in[5];
    const float* att0= (const float*)d_in[6];
    const float* bo0 = (const float*)d_in[7];
    const float* Wl1 = (const float*)d_in[8];
    const float* bl1 = (const float*)d_in[9];
    const float* Wr1 = (const float*)d_in[10];
    const float* br1 = (const float*)d_in[11];
    const float* att1= (const float*)d_in[12];
    const float* bo1 = (const float*)d_in[13];
    float* outp = (float*)d_out;

    const int N    = in_sizes[0] / 128;
    const int E    = in_sizes[1] / 2;
    const int Etot = E + N;

    // workspace layout (~55 MB)
    char* p = (char*)d_ws;
    size_t off = 0;
    const size_t feat_bytes = (size_t)N * 128 * sizeof(float);
    float* xl = (float*)(p + off); off = align_up(off + feat_bytes, 256);
    float* xr = (float*)(p + off); off = align_up(off + feat_bytes, 256);
    int* degcur = (int*)(p + off); off = align_up(off + (size_t)N * 4, 256);
    int* offs   = (int*)(p + off); off = align_up(off + (size_t)(N + 1) * 4, 256);
    int* bsum   = (int*)(p + off); off = align_up(off + 256 * 4, 256);
    int* boff   = (int*)(p + off); off = align_up(off + 256 * 4, 256);
    int* colsrc = (int*)(p + off); off = align_up(off + (size_t)Etot * 4, 256);
    float* h = outp;                         // inter-layer activation in d_out
    (void)ws_size;

    const int nbScan = (N + 255) / 256;
    const int nbEdge = (Etot + 255) / 256;

    // ---- CSR build ----
    zero_kernel<<<nbScan, 256, 0, stream>>>(degcur, N);
    hist_kernel<<<nbEdge, 256, 0, stream>>>(ei, E, Etot, degcur);
    scan1_kernel<<<nbScan, 256, 0, stream>>>(degcur, N, offs, bsum);
    scan2_kernel<<<1, 256, 0, stream>>>(bsum, nbScan, boff);
    scan3_kernel<<<nbScan, 256, 0, stream>>>(offs, boff, N, Etot, degcur);
    fill_kernel<<<nbEdge, 256, 0, stream>>>(ei, E, Etot, degcur, colsrc);

    const int nbGemm = (N + 63) / 64;
    const int nbAgg  = (N + 3) / 4;

    // ---- layer 0 ----
    gemm_dual_kernel<<<dim3(nbGemm, 2), 256, 0, stream>>>(x, Wl0, bl0, Wr0, br0, xl, xr, N);
    gat_agg_kernel<<<nbAgg, 256, 0, stream>>>(xl, xr, att0, bo0, offs, colsrc, h, N, 1);

    // ---- layer 1 ----
    gemm_dual_kernel<<<dim3(nbGemm, 2), 256, 0, stream>>>(h, Wl1, bl1, Wr1, br1, xl, xr, N);
    gat_agg_kernel<<<nbAgg, 256, 0, stream>>>(xl, xr, att1, bo1, offs, colsrc, outp, N, 0);
}

// Round 4
// 310.257 us; speedup vs baseline: 1.4436x; 1.1186x over previous
//
#include <hip/hip_runtime.h>
#include <hip/hip_bf16.h>
#include <math.h>

// ---------------------------------------------------------------------------
// GATv2 x2 layers, N=50000, d=128, E=800000 (+N self loops).
// Round 4:
//  - xl stored ONLY as packed bf16 (256B/row): halves the dominant random
//    gather traffic in agg (FETCH was ~199MB = 8 XCD x 25.6MB fp32 row reads).
//  - agg: 4 dst per wave (16-lane subgroups, 8 ch/lane, one b128 load/edge),
//    butterfly 6->4 steps, 2x edge unroll. Per-edge issue cost ~1/3.
// ---------------------------------------------------------------------------

#define LRELU_ATT 0.2f
#define LRELU_ACT 0.01f

// ---------------- CSR build ----------------

__global__ void zero_kernel(int* __restrict__ p, int n) {
    int i = blockIdx.x * blockDim.x + threadIdx.x;
    if (i < n) p[i] = 0;
}

__global__ void hist_kernel(const int* __restrict__ ei, int E, int Etot,
                            int* __restrict__ deg) {
    int e = blockIdx.x * blockDim.x + threadIdx.x;
    if (e >= Etot) return;
    int d = (e < E) ? ei[E + e] : (e - E);
    atomicAdd(&deg[d], 1);
}

__global__ void scan1_kernel(const int* __restrict__ deg, int n,
                             int* __restrict__ offs, int* __restrict__ bsum) {
    __shared__ int s[256];
    int tid = threadIdx.x;
    int i = blockIdx.x * 256 + tid;
    int v = (i < n) ? deg[i] : 0;
    s[tid] = v;
    __syncthreads();
    int sum = v;
    #pragma unroll
    for (int d = 1; d < 256; d <<= 1) {
        int t = (tid >= d) ? s[tid - d] : 0;
        __syncthreads();
        sum += t;
        s[tid] = sum;
        __syncthreads();
    }
    if (i < n) offs[i] = sum - v;
    if (tid == 255) bsum[blockIdx.x] = sum;
}

__global__ void scan2_kernel(int* __restrict__ bsum, int nb,
                             int* __restrict__ boff) {
    __shared__ int s[256];
    int tid = threadIdx.x;
    int v = (tid < nb) ? bsum[tid] : 0;
    s[tid] = v;
    __syncthreads();
    int sum = v;
    #pragma unroll
    for (int d = 1; d < 256; d <<= 1) {
        int t = (tid >= d) ? s[tid - d] : 0;
        __syncthreads();
        sum += t;
        s[tid] = sum;
        __syncthreads();
    }
    if (tid < nb) boff[tid] = sum - v;
}

__global__ void scan3_kernel(int* __restrict__ offs, const int* __restrict__ boff,
                             int n, int Etot, int* __restrict__ cursor) {
    int i = blockIdx.x * 256 + threadIdx.x;
    if (i < n) {
        int o = offs[i] + boff[blockIdx.x];
        offs[i] = o;
        cursor[i] = o;
    }
    if (i == 0) offs[n] = Etot;
}

__global__ void fill_kernel(const int* __restrict__ ei, int E, int Etot,
                            int* __restrict__ cursor, int* __restrict__ col_src) {
    int e = blockIdx.x * blockDim.x + threadIdx.x;
    if (e >= Etot) return;
    int s, d;
    if (e < E) { s = ei[e]; d = ei[E + e]; }
    else       { s = d = e - E; }
    int pos = atomicAdd(&cursor[d], 1);
    col_src[pos] = s;
}

// ---------------- helpers ----------------

__device__ __forceinline__ unsigned short f2bf(float f) {
    unsigned u = __float_as_uint(f);
    unsigned r = (u + 0x7fffu + ((u >> 16) & 1u)) >> 16;   // RNE
    return (unsigned short)r;
}

__device__ __forceinline__ void unpack8(uint4 q, float* v) {
    v[0] = __uint_as_float(q.x << 16); v[1] = __uint_as_float(q.x & 0xffff0000u);
    v[2] = __uint_as_float(q.y << 16); v[3] = __uint_as_float(q.y & 0xffff0000u);
    v[4] = __uint_as_float(q.z << 16); v[5] = __uint_as_float(q.z & 0xffff0000u);
    v[6] = __uint_as_float(q.w << 16); v[7] = __uint_as_float(q.w & 0xffff0000u);
}

__device__ __forceinline__ float logit8(const float* v, const float* xrv,
                                        const float* attv) {
    float p = 0.f;
    #pragma unroll
    for (int j = 0; j < 8; ++j) {
        float m = v[j] + xrv[j];
        m = m > 0.f ? m : LRELU_ATT * m;
        p = fmaf(m, attv[j], p);
    }
    return p;
}

// ---------------- dual GEMM: xlb(bf16) = X@Wl+bl ; xr(f32) = X@Wr+br -------
// block: 256 thr; tile 64 rows x 128 cols; thread = 8 rows x 4 cols.

__global__ __launch_bounds__(256) void gemm_dual_kernel(
    const float* __restrict__ X,
    const float* __restrict__ Wl, const float* __restrict__ bl,
    const float* __restrict__ Wr, const float* __restrict__ br,
    unsigned short* __restrict__ xlb, float* __restrict__ xr, int n) {
    __shared__ float xs[64 * 128];
    const int tid = threadIdx.x;
    const int base = blockIdx.x * 64;

    const float4* X4 = (const float4*)X;
    float4* xs4 = (float4*)xs;
    #pragma unroll
    for (int i = 0; i < 8; ++i) {
        int f = tid + i * 256;
        int row = base + (f >> 5);
        float4 v = make_float4(0.f, 0.f, 0.f, 0.f);
        if (row < n) v = X4[(size_t)base * 32 + f];
        xs4[f] = v;
    }
    __syncthreads();

    const int isR = blockIdx.y;
    const float* W  = isR ? Wr : Wl;
    const float* bb = isR ? br : bl;

    const int tc = tid & 31;
    const int tr = tid >> 5;
    const int col0 = tc * 4;
    const int r0 = tr * 8;

    float4 acc[8];
    #pragma unroll
    for (int r = 0; r < 8; ++r) acc[r] = make_float4(0.f, 0.f, 0.f, 0.f);

    for (int k = 0; k < 128; k += 4) {
        float4 wv0 = *(const float4*)(W + (size_t)(k + 0) * 128 + col0);
        float4 wv1 = *(const float4*)(W + (size_t)(k + 1) * 128 + col0);
        float4 wv2 = *(const float4*)(W + (size_t)(k + 2) * 128 + col0);
        float4 wv3 = *(const float4*)(W + (size_t)(k + 3) * 128 + col0);
        #pragma unroll
        for (int r = 0; r < 8; ++r) {
            float4 xv = *(const float4*)(xs + (r0 + r) * 128 + k);
            acc[r].x += xv.x * wv0.x + xv.y * wv1.x + xv.z * wv2.x + xv.w * wv3.x;
            acc[r].y += xv.x * wv0.y + xv.y * wv1.y + xv.z * wv2.y + xv.w * wv3.y;
            acc[r].z += xv.x * wv0.z + xv.y * wv1.z + xv.z * wv2.z + xv.w * wv3.z;
            acc[r].w += xv.x * wv0.w + xv.y * wv1.w + xv.z * wv2.w + xv.w * wv3.w;
        }
    }

    float4 bv = *(const float4*)(bb + col0);
    if (isR) {
        #pragma unroll
        for (int r = 0; r < 8; ++r) {
            int row = base + r0 + r;
            if (row < n) {
                float4 o = make_float4(acc[r].x + bv.x, acc[r].y + bv.y,
                                       acc[r].z + bv.z, acc[r].w + bv.w);
                *(float4*)(xr + (size_t)row * 128 + col0) = o;
            }
        }
    } else {
        #pragma unroll
        for (int r = 0; r < 8; ++r) {
            int row = base + r0 + r;
            if (row < n) {
                ushort4 o;
                o.x = f2bf(acc[r].x + bv.x);
                o.y = f2bf(acc[r].y + bv.y);
                o.z = f2bf(acc[r].z + bv.z);
                o.w = f2bf(acc[r].w + bv.w);
                *(ushort4*)(xlb + (size_t)row * 128 + col0) = o;
            }
        }
    }
}

// ---------------- fused attention + aggregation ----------------
// 4 dst nodes per wave: 16-lane subgroup per node, lane owns 8 channels
// (one uint4 = 8 bf16 per gather). Butterfly = 4 steps within subgroup.
// softmax WITHOUT max-shift: logits ~N(0,1.3^2), exp safe in fp32.

__global__ __launch_bounds__(256) void gat_agg_kernel(
    const unsigned short* __restrict__ xlb, const float* __restrict__ xr,
    const float* __restrict__ att, const float* __restrict__ bo,
    const int* __restrict__ offs, const int* __restrict__ col,
    float* __restrict__ out, int n, int apply_act) {
    const int lane = threadIdx.x & 63;
    const int sub  = lane >> 4;
    const int sl   = lane & 15;
    const int gw   = (blockIdx.x * blockDim.x + threadIdx.x) >> 6;
    const int node = gw * 4 + sub;
    const bool valid = node < n;

    const float4* xr4  = (const float4*)xr;
    const float4* att4 = (const float4*)att;
    float xrv[8], attv[8];
    {
        float4 a = make_float4(0.f, 0.f, 0.f, 0.f), b = a;
        if (valid) {
            a = xr4[(size_t)node * 32 + sl * 2];
            b = xr4[(size_t)node * 32 + sl * 2 + 1];
        }
        xrv[0]=a.x; xrv[1]=a.y; xrv[2]=a.z; xrv[3]=a.w;
        xrv[4]=b.x; xrv[5]=b.y; xrv[6]=b.z; xrv[7]=b.w;
        float4 c = att4[sl * 2], d = att4[sl * 2 + 1];
        attv[0]=c.x; attv[1]=c.y; attv[2]=c.z; attv[3]=c.w;
        attv[4]=d.x; attv[5]=d.y; attv[6]=d.z; attv[7]=d.w;
    }

    float acc[8];
    #pragma unroll
    for (int j = 0; j < 8; ++j) acc[j] = 0.f;
    float den = 0.f;

    int b = 0, cnt = 0;
    if (valid) { b = offs[node]; cnt = offs[node + 1] - b; }
    const uint4* xq = (const uint4*)xlb;

    int t = 0;
    for (; t + 2 <= cnt; t += 2) {
        const int s0 = col[b + t], s1 = col[b + t + 1];
        uint4 q0 = xq[(size_t)s0 * 16 + sl];
        uint4 q1 = xq[(size_t)s1 * 16 + sl];
        float v0[8], v1[8];
        unpack8(q0, v0);
        unpack8(q1, v1);
        float p0 = logit8(v0, xrv, attv);
        float p1 = logit8(v1, xrv, attv);
        p0 += __shfl_xor(p0, 1, 64);  p1 += __shfl_xor(p1, 1, 64);
        p0 += __shfl_xor(p0, 2, 64);  p1 += __shfl_xor(p1, 2, 64);
        p0 += __shfl_xor(p0, 4, 64);  p1 += __shfl_xor(p1, 4, 64);
        p0 += __shfl_xor(p0, 8, 64);  p1 += __shfl_xor(p1, 8, 64);
        const float e0 = __expf(p0), e1 = __expf(p1);
        #pragma unroll
        for (int j = 0; j < 8; ++j)
            acc[j] = fmaf(e1, v1[j], fmaf(e0, v0[j], acc[j]));
        den += e0 + e1;
    }
    if (t < cnt) {
        const int s0 = col[b + t];
        uint4 q0 = xq[(size_t)s0 * 16 + sl];
        float v0[8];
        unpack8(q0, v0);
        float p0 = logit8(v0, xrv, attv);
        p0 += __shfl_xor(p0, 1, 64);
        p0 += __shfl_xor(p0, 2, 64);
        p0 += __shfl_xor(p0, 4, 64);
        p0 += __shfl_xor(p0, 8, 64);
        const float e0 = __expf(p0);
        #pragma unroll
        for (int j = 0; j < 8; ++j) acc[j] = fmaf(e0, v0[j], acc[j]);
        den += e0;
    }

    if (valid) {
        const float inv = 1.f / (den + 1e-16f);
        float4 b1 = ((const float4*)bo)[sl * 2];
        float4 b2 = ((const float4*)bo)[sl * 2 + 1];
        float bov[8] = {b1.x, b1.y, b1.z, b1.w, b2.x, b2.y, b2.z, b2.w};
        float o[8];
        #pragma unroll
        for (int j = 0; j < 8; ++j) {
            float v = acc[j] * inv + bov[j];
            if (apply_act) v = v > 0.f ? v : LRELU_ACT * v;
            o[j] = v;
        }
        float4* o4 = (float4*)(out + (size_t)node * 128 + sl * 8);
        o4[0] = make_float4(o[0], o[1], o[2], o[3]);
        o4[1] = make_float4(o[4], o[5], o[6], o[7]);
    }
}

// ---------------- host launch ----------------

static inline size_t align_up(size_t x, size_t a) { return (x + a - 1) & ~(a - 1); }

extern "C" void kernel_launch(void* const* d_in, const int* in_sizes, int n_in,
                              void* d_out, int out_size, void* d_ws, size_t ws_size,
                              hipStream_t stream) {
    const float* x   = (const float*)d_in[0];
    const int*   ei  = (const int*)d_in[1];     // int32 per harness contract
    const float* Wl0 = (const float*)d_in[2];
    const float* bl0 = (const float*)d_in[3];
    const float* Wr0 = (const float*)d_in[4];
    const float* br0 = (const float*)d_in[5];
    const float* att0= (const float*)d_in[6];
    const float* bo0 = (const float*)d_in[7];
    const float* Wl1 = (const float*)d_in[8];
    const float* bl1 = (const float*)d_in[9];
    const float* Wr1 = (const float*)d_in[10];
    const float* br1 = (const float*)d_in[11];
    const float* att1= (const float*)d_in[12];
    const float* bo1 = (const float*)d_in[13];
    float* outp = (float*)d_out;

    const int N    = in_sizes[0] / 128;
    const int E    = in_sizes[1] / 2;
    const int Etot = E + N;

    // workspace layout (~42 MB)
    char* p = (char*)d_ws;
    size_t off = 0;
    unsigned short* xlb = (unsigned short*)(p + off);
    off = align_up(off + (size_t)N * 128 * 2, 256);
    float* xr = (float*)(p + off);
    off = align_up(off + (size_t)N * 128 * 4, 256);
    int* degcur = (int*)(p + off); off = align_up(off + (size_t)N * 4, 256);
    int* offs   = (int*)(p + off); off = align_up(off + (size_t)(N + 1) * 4, 256);
    int* bsum   = (int*)(p + off); off = align_up(off + 256 * 4, 256);
    int* boff   = (int*)(p + off); off = align_up(off + 256 * 4, 256);
    int* colsrc = (int*)(p + off); off = align_up(off + (size_t)Etot * 4, 256);
    float* h = outp;                         // inter-layer activation in d_out
    (void)ws_size;

    const int nbScan = (N + 255) / 256;
    const int nbEdge = (Etot + 255) / 256;

    // ---- CSR build ----
    zero_kernel<<<nbScan, 256, 0, stream>>>(degcur, N);
    hist_kernel<<<nbEdge, 256, 0, stream>>>(ei, E, Etot, degcur);
    scan1_kernel<<<nbScan, 256, 0, stream>>>(degcur, N, offs, bsum);
    scan2_kernel<<<1, 256, 0, stream>>>(bsum, nbScan, boff);
    scan3_kernel<<<nbScan, 256, 0, stream>>>(offs, boff, N, Etot, degcur);
    fill_kernel<<<nbEdge, 256, 0, stream>>>(ei, E, Etot, degcur, colsrc);

    const int nbGemm = (N + 63) / 64;
    const int nbAgg  = (N + 15) / 16;        // 16 dst nodes per 256-thr block

    // ---- layer 0 ----
    gemm_dual_kernel<<<dim3(nbGemm, 2), 256, 0, stream>>>(x, Wl0, bl0, Wr0, br0, xlb, xr, N);
    gat_agg_kernel<<<nbAgg, 256, 0, stream>>>(xlb, xr, att0, bo0, offs, colsrc, h, N, 1);

    // ---- layer 1 ----
    gemm_dual_kernel<<<dim3(nbGemm, 2), 256, 0, stream>>>(h, Wl1, bl1, Wr1, br1, xlb, xr, N);
    gat_agg_kernel<<<nbAgg, 256, 0, stream>>>(xlb, xr, att1, bo1, offs, colsrc, outp, N, 0);
}

// Round 5
// 252.312 us; speedup vs baseline: 1.7752x; 1.2297x over previous
//
#include <hip/hip_runtime.h>
#include <hip/hip_bf16.h>
#include <math.h>

// ---------------------------------------------------------------------------
// GATv2 x2 layers, N=50000, d=128, E=800000 (+N self loops).
// Round 5: GEMM moved to bf16 MFMA (mfma_f32_16x16x32_bf16).
//  - W matrices pre-swizzled once into B-fragment order (wconv_kernel).
//  - gemm_mfma: wave = 32 rows x 128 cols, A-frags in reg (inline f32->bf16
//    cvt for layer 0; h is already bf16 for layer 1), 128 MFMAs/wave, no LDS.
//  - agg layer-0 writes h as bf16 (halves layer-1 A-read); layout unchanged.
// ---------------------------------------------------------------------------

#define LRELU_ATT 0.2f
#define LRELU_ACT 0.01f

typedef __attribute__((ext_vector_type(8))) short bf16x8;
typedef __attribute__((ext_vector_type(4))) float f32x4;

// ---------------- CSR build ----------------

__global__ void zero_kernel(int* __restrict__ p, int n) {
    int i = blockIdx.x * blockDim.x + threadIdx.x;
    if (i < n) p[i] = 0;
}

__global__ void hist_kernel(const int* __restrict__ ei, int E, int Etot,
                            int* __restrict__ deg) {
    int e = blockIdx.x * blockDim.x + threadIdx.x;
    if (e >= Etot) return;
    int d = (e < E) ? ei[E + e] : (e - E);
    atomicAdd(&deg[d], 1);
}

__global__ void scan1_kernel(const int* __restrict__ deg, int n,
                             int* __restrict__ offs, int* __restrict__ bsum) {
    __shared__ int s[256];
    int tid = threadIdx.x;
    int i = blockIdx.x * 256 + tid;
    int v = (i < n) ? deg[i] : 0;
    s[tid] = v;
    __syncthreads();
    int sum = v;
    #pragma unroll
    for (int d = 1; d < 256; d <<= 1) {
        int t = (tid >= d) ? s[tid - d] : 0;
        __syncthreads();
        sum += t;
        s[tid] = sum;
        __syncthreads();
    }
    if (i < n) offs[i] = sum - v;
    if (tid == 255) bsum[blockIdx.x] = sum;
}

__global__ void scan2_kernel(int* __restrict__ bsum, int nb,
                             int* __restrict__ boff) {
    __shared__ int s[256];
    int tid = threadIdx.x;
    int v = (tid < nb) ? bsum[tid] : 0;
    s[tid] = v;
    __syncthreads();
    int sum = v;
    #pragma unroll
    for (int d = 1; d < 256; d <<= 1) {
        int t = (tid >= d) ? s[tid - d] : 0;
        __syncthreads();
        sum += t;
        s[tid] = sum;
        __syncthreads();
    }
    if (tid < nb) boff[tid] = sum - v;
}

__global__ void scan3_kernel(int* __restrict__ offs, const int* __restrict__ boff,
                             int n, int Etot, int* __restrict__ cursor) {
    int i = blockIdx.x * 256 + threadIdx.x;
    if (i < n) {
        int o = offs[i] + boff[blockIdx.x];
        offs[i] = o;
        cursor[i] = o;
    }
    if (i == 0) offs[n] = Etot;
}

__global__ void fill_kernel(const int* __restrict__ ei, int E, int Etot,
                            int* __restrict__ cursor, int* __restrict__ col_src) {
    int e = blockIdx.x * blockDim.x + threadIdx.x;
    if (e >= Etot) return;
    int s, d;
    if (e < E) { s = ei[e]; d = ei[E + e]; }
    else       { s = d = e - E; }
    int pos = atomicAdd(&cursor[d], 1);
    col_src[pos] = s;
}

// ---------------- helpers ----------------

__device__ __forceinline__ unsigned short f2bf(float f) {
    unsigned u = __float_as_uint(f);
    unsigned r = (u + 0x7fffu + ((u >> 16) & 1u)) >> 16;   // RNE
    return (unsigned short)r;
}

__device__ __forceinline__ bf16x8 pack8(float4 a, float4 b) {
    union { bf16x8 v; unsigned short u[8]; } t;
    t.u[0] = f2bf(a.x); t.u[1] = f2bf(a.y); t.u[2] = f2bf(a.z); t.u[3] = f2bf(a.w);
    t.u[4] = f2bf(b.x); t.u[5] = f2bf(b.y); t.u[6] = f2bf(b.z); t.u[7] = f2bf(b.w);
    return t.v;
}

__device__ __forceinline__ bf16x8 ldbf8(const unsigned short* p) {
    union { uint4 q; bf16x8 v; } t;
    t.q = *(const uint4*)p;
    return t.v;
}

__device__ __forceinline__ void unpack8(uint4 q, float* v) {
    v[0] = __uint_as_float(q.x << 16); v[1] = __uint_as_float(q.x & 0xffff0000u);
    v[2] = __uint_as_float(q.y << 16); v[3] = __uint_as_float(q.y & 0xffff0000u);
    v[4] = __uint_as_float(q.z << 16); v[5] = __uint_as_float(q.z & 0xffff0000u);
    v[6] = __uint_as_float(q.w << 16); v[7] = __uint_as_float(q.w & 0xffff0000u);
}

__device__ __forceinline__ float logit8(const float* v, const float* xrv,
                                        const float* attv) {
    float p = 0.f;
    #pragma unroll
    for (int j = 0; j < 8; ++j) {
        float m = v[j] + xrv[j];
        m = m > 0.f ? m : LRELU_ATT * m;
        p = fmaf(m, attv[j], p);
    }
    return p;
}

// ---------------- W pre-swizzle into MFMA B-fragment order ----------------
// B frag for (ks, ct): lane l, elem j holds W[ks*32 + (l>>4)*8 + j][ct*16 + (l&15)].
// Linear frag address: ((ks*8 + ct)*64 + l)*8 + j.  4 matrices: Wl0,Wr0,Wl1,Wr1.

__global__ void wconv_kernel(const float* __restrict__ W0, const float* __restrict__ W1,
                             const float* __restrict__ W2, const float* __restrict__ W3,
                             unsigned short* __restrict__ Wb) {
    int g = blockIdx.x * 256 + threadIdx.x;    // 0 .. 4*16384-1
    int m = g >> 14;
    int f = g & 16383;
    int j = f & 7, l = (f >> 3) & 63, ct = (f >> 9) & 7, ks = f >> 12;
    int row = ks * 32 + ((l >> 4) << 3) + j;
    int col = ct * 16 + (l & 15);
    const float* W = m == 0 ? W0 : m == 1 ? W1 : m == 2 ? W2 : W3;
    Wb[g] = f2bf(W[row * 128 + col]);
}

// ---------------- MFMA dual GEMM: xlb(bf16)=X@Wl+bl ; xr(f32)=X@Wr+br ------
// block = 128 thr = 2 waves; wave = 32 rows x 128 cols, K=128.
// A frags held in registers (8 x bf16x8); B frags streamed from L2 (Wb).

template<bool INF32>
__global__ __launch_bounds__(128) void gemm_mfma_kernel(
    const void* __restrict__ Xin,
    const unsigned short* __restrict__ Wb,   // layer base: l frags, then r frags
    const float* __restrict__ bl, const float* __restrict__ br,
    unsigned short* __restrict__ xlb, float* __restrict__ xr, int n) {
    const int tid  = threadIdx.x;
    const int wave = tid >> 6, lane = tid & 63;
    const int rowbase = blockIdx.x * 64 + wave * 32;
    const int lrow = lane & 15;
    const int kgrp = lane >> 4;

    bf16x8 af[2][4];
    #pragma unroll
    for (int rt = 0; rt < 2; ++rt) {
        const int row = rowbase + rt * 16 + lrow;
        const bool ok = row < n;
        #pragma unroll
        for (int ks = 0; ks < 4; ++ks) {
            const int k0 = ks * 32 + kgrp * 8;
            if (INF32) {
                const float* X = (const float*)Xin;
                float4 a = make_float4(0.f, 0.f, 0.f, 0.f), b = a;
                if (ok) {
                    a = *(const float4*)(X + (size_t)row * 128 + k0);
                    b = *(const float4*)(X + (size_t)row * 128 + k0 + 4);
                }
                af[rt][ks] = pack8(a, b);
            } else {
                const unsigned short* X = (const unsigned short*)Xin;
                union { uint4 q; bf16x8 v; } t;
                t.q = make_uint4(0u, 0u, 0u, 0u);
                if (ok) t.q = *(const uint4*)(X + (size_t)row * 128 + k0);
                af[rt][ks] = t.v;
            }
        }
    }

    #pragma unroll
    for (int m = 0; m < 2; ++m) {
        const unsigned short* wb = Wb + m * 16384;
        f32x4 acc[2][8];
        #pragma unroll
        for (int rt = 0; rt < 2; ++rt)
            #pragma unroll
            for (int ct = 0; ct < 8; ++ct)
                acc[rt][ct] = (f32x4){0.f, 0.f, 0.f, 0.f};

        #pragma unroll
        for (int ct = 0; ct < 8; ++ct) {
            #pragma unroll
            for (int ks = 0; ks < 4; ++ks) {
                bf16x8 bf = ldbf8(wb + ((ks * 8 + ct) * 64 + lane) * 8);
                acc[0][ct] = __builtin_amdgcn_mfma_f32_16x16x32_bf16(af[0][ks], bf, acc[0][ct], 0, 0, 0);
                acc[1][ct] = __builtin_amdgcn_mfma_f32_16x16x32_bf16(af[1][ks], bf, acc[1][ct], 0, 0, 0);
            }
        }

        const float* bias = m ? br : bl;
        #pragma unroll
        for (int rt = 0; rt < 2; ++rt) {
            #pragma unroll
            for (int ct = 0; ct < 8; ++ct) {
                const int col = ct * 16 + lrow;           // D: col = lane&15
                const float bv = bias[col];
                #pragma unroll
                for (int i = 0; i < 4; ++i) {
                    const int row = rowbase + rt * 16 + kgrp * 4 + i;  // D: row=(lane>>4)*4+i
                    if (row < n) {
                        float v = acc[rt][ct][i] + bv;
                        if (m == 0) xlb[(size_t)row * 128 + col] = f2bf(v);
                        else        xr [(size_t)row * 128 + col] = v;
                    }
                }
            }
        }
    }
}

// ---------------- fused attention + aggregation ----------------
// 4 dst nodes per wave: 16-lane subgroup per node, lane owns 8 channels.
// OUTBF: write bf16 (inter-layer h, with leaky 0.01); else f32 (final out).

template<bool OUTBF>
__global__ __launch_bounds__(256) void gat_agg_kernel(
    const unsigned short* __restrict__ xlb, const float* __restrict__ xr,
    const float* __restrict__ att, const float* __restrict__ bo,
    const int* __restrict__ offs, const int* __restrict__ col,
    float* __restrict__ outf, unsigned short* __restrict__ outb,
    int n, int apply_act) {
    const int lane = threadIdx.x & 63;
    const int sub  = lane >> 4;
    const int sl   = lane & 15;
    const int gw   = (blockIdx.x * blockDim.x + threadIdx.x) >> 6;
    const int node = gw * 4 + sub;
    const bool valid = node < n;

    const float4* xr4  = (const float4*)xr;
    const float4* att4 = (const float4*)att;
    float xrv[8], attv[8];
    {
        float4 a = make_float4(0.f, 0.f, 0.f, 0.f), b = a;
        if (valid) {
            a = xr4[(size_t)node * 32 + sl * 2];
            b = xr4[(size_t)node * 32 + sl * 2 + 1];
        }
        xrv[0]=a.x; xrv[1]=a.y; xrv[2]=a.z; xrv[3]=a.w;
        xrv[4]=b.x; xrv[5]=b.y; xrv[6]=b.z; xrv[7]=b.w;
        float4 c = att4[sl * 2], d = att4[sl * 2 + 1];
        attv[0]=c.x; attv[1]=c.y; attv[2]=c.z; attv[3]=c.w;
        attv[4]=d.x; attv[5]=d.y; attv[6]=d.z; attv[7]=d.w;
    }

    float acc[8];
    #pragma unroll
    for (int j = 0; j < 8; ++j) acc[j] = 0.f;
    float den = 0.f;

    int b = 0, cnt = 0;
    if (valid) { b = offs[node]; cnt = offs[node + 1] - b; }
    const uint4* xq = (const uint4*)xlb;

    int t = 0;
    for (; t + 2 <= cnt; t += 2) {
        const int s0 = col[b + t], s1 = col[b + t + 1];
        uint4 q0 = xq[(size_t)s0 * 16 + sl];
        uint4 q1 = xq[(size_t)s1 * 16 + sl];
        float v0[8], v1[8];
        unpack8(q0, v0);
        unpack8(q1, v1);
        float p0 = logit8(v0, xrv, attv);
        float p1 = logit8(v1, xrv, attv);
        p0 += __shfl_xor(p0, 1, 64);  p1 += __shfl_xor(p1, 1, 64);
        p0 += __shfl_xor(p0, 2, 64);  p1 += __shfl_xor(p1, 2, 64);
        p0 += __shfl_xor(p0, 4, 64);  p1 += __shfl_xor(p1, 4, 64);
        p0 += __shfl_xor(p0, 8, 64);  p1 += __shfl_xor(p1, 8, 64);
        const float e0 = __expf(p0), e1 = __expf(p1);
        #pragma unroll
        for (int j = 0; j < 8; ++j)
            acc[j] = fmaf(e1, v1[j], fmaf(e0, v0[j], acc[j]));
        den += e0 + e1;
    }
    if (t < cnt) {
        const int s0 = col[b + t];
        uint4 q0 = xq[(size_t)s0 * 16 + sl];
        float v0[8];
        unpack8(q0, v0);
        float p0 = logit8(v0, xrv, attv);
        p0 += __shfl_xor(p0, 1, 64);
        p0 += __shfl_xor(p0, 2, 64);
        p0 += __shfl_xor(p0, 4, 64);
        p0 += __shfl_xor(p0, 8, 64);
        const float e0 = __expf(p0);
        #pragma unroll
        for (int j = 0; j < 8; ++j) acc[j] = fmaf(e0, v0[j], acc[j]);
        den += e0;
    }

    if (valid) {
        const float inv = 1.f / (den + 1e-16f);
        float4 b1 = ((const float4*)bo)[sl * 2];
        float4 b2 = ((const float4*)bo)[sl * 2 + 1];
        float bov[8] = {b1.x, b1.y, b1.z, b1.w, b2.x, b2.y, b2.z, b2.w};
        float o[8];
        #pragma unroll
        for (int j = 0; j < 8; ++j) {
            float v = acc[j] * inv + bov[j];
            if (apply_act) v = v > 0.f ? v : LRELU_ACT * v;
            o[j] = v;
        }
        if (OUTBF) {
            ushort4 u0, u1;
            u0.x = f2bf(o[0]); u0.y = f2bf(o[1]); u0.z = f2bf(o[2]); u0.w = f2bf(o[3]);
            u1.x = f2bf(o[4]); u1.y = f2bf(o[5]); u1.z = f2bf(o[6]); u1.w = f2bf(o[7]);
            ushort4* ob = (ushort4*)(outb + (size_t)node * 128 + sl * 8);
            ob[0] = u0; ob[1] = u1;
        } else {
            float4* o4 = (float4*)(outf + (size_t)node * 128 + sl * 8);
            o4[0] = make_float4(o[0], o[1], o[2], o[3]);
            o4[1] = make_float4(o[4], o[5], o[6], o[7]);
        }
    }
}

// ---------------- host launch ----------------

static inline size_t align_up(size_t x, size_t a) { return (x + a - 1) & ~(a - 1); }

extern "C" void kernel_launch(void* const* d_in, const int* in_sizes, int n_in,
                              void* d_out, int out_size, void* d_ws, size_t ws_size,
                              hipStream_t stream) {
    const float* x   = (const float*)d_in[0];
    const int*   ei  = (const int*)d_in[1];     // int32 per harness contract
    const float* Wl0 = (const float*)d_in[2];
    const float* bl0 = (const float*)d_in[3];
    const float* Wr0 = (const float*)d_in[4];
    const float* br0 = (const float*)d_in[5];
    const float* att0= (const float*)d_in[6];
    const float* bo0 = (const float*)d_in[7];
    const float* Wl1 = (const float*)d_in[8];
    const float* bl1 = (const float*)d_in[9];
    const float* Wr1 = (const float*)d_in[10];
    const float* br1 = (const float*)d_in[11];
    const float* att1= (const float*)d_in[12];
    const float* bo1 = (const float*)d_in[13];
    float* outp = (float*)d_out;

    const int N    = in_sizes[0] / 128;
    const int E    = in_sizes[1] / 2;
    const int Etot = E + N;

    // workspace layout (~46 MB)
    char* p = (char*)d_ws;
    size_t off = 0;
    unsigned short* xlb = (unsigned short*)(p + off);
    off = align_up(off + (size_t)N * 128 * 2, 256);
    float* xr = (float*)(p + off);
    off = align_up(off + (size_t)N * 128 * 4, 256);
    unsigned short* Wb = (unsigned short*)(p + off);
    off = align_up(off + (size_t)4 * 16384 * 2, 256);
    int* degcur = (int*)(p + off); off = align_up(off + (size_t)N * 4, 256);
    int* offs   = (int*)(p + off); off = align_up(off + (size_t)(N + 1) * 4, 256);
    int* bsum   = (int*)(p + off); off = align_up(off + 256 * 4, 256);
    int* boff   = (int*)(p + off); off = align_up(off + 256 * 4, 256);
    int* colsrc = (int*)(p + off); off = align_up(off + (size_t)Etot * 4, 256);
    unsigned short* hb = (unsigned short*)d_out;   // inter-layer bf16 h (12.8MB of 25.6)
    (void)ws_size;

    const int nbScan = (N + 255) / 256;
    const int nbEdge = (Etot + 255) / 256;

    // ---- CSR build + W swizzle ----
    zero_kernel<<<nbScan, 256, 0, stream>>>(degcur, N);
    hist_kernel<<<nbEdge, 256, 0, stream>>>(ei, E, Etot, degcur);
    scan1_kernel<<<nbScan, 256, 0, stream>>>(degcur, N, offs, bsum);
    scan2_kernel<<<1, 256, 0, stream>>>(bsum, nbScan, boff);
    scan3_kernel<<<nbScan, 256, 0, stream>>>(offs, boff, N, Etot, degcur);
    fill_kernel<<<nbEdge, 256, 0, stream>>>(ei, E, Etot, degcur, colsrc);
    wconv_kernel<<<256, 256, 0, stream>>>(Wl0, Wr0, Wl1, Wr1, Wb);

    const int nbGemm = (N + 63) / 64;
    const int nbAgg  = (N + 15) / 16;

    // ---- layer 0 ----
    gemm_mfma_kernel<true><<<nbGemm, 128, 0, stream>>>(
        (const void*)x, Wb, bl0, br0, xlb, xr, N);
    gat_agg_kernel<true><<<nbAgg, 256, 0, stream>>>(
        xlb, xr, att0, bo0, offs, colsrc, nullptr, hb, N, 1);

    // ---- layer 1 ----
    gemm_mfma_kernel<false><<<nbGemm, 128, 0, stream>>>(
        (const void*)hb, Wb + 2 * 16384, bl1, br1, xlb, xr, N);
    gat_agg_kernel<false><<<nbAgg, 256, 0, stream>>>(
        xlb, xr, att1, bo1, offs, colsrc, outp, nullptr, N, 0);
}